// Round 7
// baseline (351.056 us; speedup 1.0000x reference)
//
#include <hip/hip_runtime.h>

// B=8, T=1024, D=1024, H=16, DH=64.
// Column softmax (axis=-2): attn[q,k] = exp(S[q,k])/sum_q' exp(S[q',k]).
// rcpL folded into V (Vts = V * rcpL), so K3 is O = exp2(S*C2) @ Vts.

typedef __bf16 bf16_t;
typedef __bf16 bf16x8 __attribute__((ext_vector_type(8)));
typedef float f32x4 __attribute__((ext_vector_type(4)));
typedef unsigned short u16x8 __attribute__((ext_vector_type(8)));

#define DEV __device__ __forceinline__
#define C2 0.18033688f  // DH^-0.5 * log2(e)

DEV void gld_lds16(const bf16_t* g, bf16_t* l) {
  __builtin_amdgcn_global_load_lds(
      (const __attribute__((address_space(1))) unsigned int*)g,
      (__attribute__((address_space(3))) unsigned int*)l, 16, 0, 0);
}

// exp2 via v_exp_f32; upper clamp only (underflow->0 fine); finite always.
DEV float exp2c(float x) { return __builtin_amdgcn_exp2f(fminf(x, 30.f)); }
DEV float sanit(float v) { return (v == v) ? fminf(fmaxf(v, -1e4f), 1e4f) : 0.f; }

// Swizzled chunk (8 bf16 = 16B) offsets in elements. Swizzle baked into the
// staging GLOBAL address so the LDS side stays linear (global_load_lds req).
DEV int sw64(int r, int kc) { return r * 64 + (((kc ^ (r + (r >> 3))) & 7) << 3); }
DEV int sw32(int r, int kc) { return r * 32 + (((kc ^ r ^ (r >> 2)) & 3) << 3); }

DEV f32x4 mfma16(bf16x8 a, bf16x8 b, f32x4 c) {
  return __builtin_amdgcn_mfma_f32_16x16x32_bf16(a, b, c, 0, 0, 0);
}

// ---- dtype probe: bf16 data has exp<=~134; fp32 misread shows exp>=160 -----
__global__ void detect_dtype(const unsigned short* x, int* flag) {
  __shared__ int smax;
  if (threadIdx.x == 0) smax = 0;
  __syncthreads();
  int m = 0;
  for (int i = threadIdx.x; i < 16384; i += 256) {
    int e = (x[i] >> 7) & 0xFF;
    m = m > e ? m : e;
  }
  atomicMax(&smax, m);
  __syncthreads();
  if (threadIdx.x == 0) *flag = (smax >= 160) ? 1 : 0;
}

// ---- canonicalize all 3 inputs to bf16 in one kernel ------------------------
__global__ void convert_in(const void* __restrict__ x, const void* __restrict__ wq,
                           const void* __restrict__ wp, bf16_t* __restrict__ xb,
                           bf16_t* __restrict__ wqb, bf16_t* __restrict__ wpb,
                           const int* __restrict__ flag) {
  int i = blockIdx.x * 256 + threadIdx.x;  // vec8 index, total 1572864
  const void* src;
  bf16_t* dst;
  int off;
  if (i < 1048576) { src = x; dst = xb; off = i; }
  else if (i < 1441792) { src = wq; dst = wqb; off = i - 1048576; }
  else { src = wp; dst = wpb; off = i - 1441792; }
  if (*flag) {
    const float4* s = (const float4*)src;
    float4 a = s[off * 2], b = s[off * 2 + 1];
    bf16x8 o;
    o[0] = (bf16_t)a.x; o[1] = (bf16_t)a.y; o[2] = (bf16_t)a.z; o[3] = (bf16_t)a.w;
    o[4] = (bf16_t)b.x; o[5] = (bf16_t)b.y; o[6] = (bf16_t)b.z; o[7] = (bf16_t)b.w;
    *(bf16x8*)(dst + (size_t)off * 8) = o;
  } else {
    ((u16x8*)dst)[off] = ((const u16x8*)src)[off];
  }
}

// --------- C[m][n] = sum_k A[m][k]*B[n][k], 128x128 tile, BK=32 -------------
__global__ __launch_bounds__(256, 2)
void gemm_bt(const bf16_t* __restrict__ A, int lda, const bf16_t* __restrict__ B,
             bf16_t* __restrict__ Cb, float* __restrict__ Cf, int ldc,
             int K, const int* __restrict__ f32flag) {
  __shared__ bf16_t sA[128 * 32];
  __shared__ bf16_t sB[128 * 32];
  const int tid = threadIdx.x;
  const int wave = tid >> 6, lane = tid & 63;
  const int l = lane & 15, quad = lane >> 4;
  const int row0 = blockIdx.y * 128, col0 = blockIdx.x * 128;
  const int wm = (wave >> 1) * 64, wn = (wave & 1) * 64;
  f32x4 acc[4][4];
#pragma unroll
  for (int i = 0; i < 4; ++i)
#pragma unroll
    for (int j = 0; j < 4; ++j) acc[i][j] = f32x4{0.f, 0.f, 0.f, 0.f};

  for (int k0 = 0; k0 < K; k0 += 32) {
    __syncthreads();
#pragma unroll
    for (int t = 0; t < 2; ++t) {
      int base = t * 256 + wave * 64;
      int n = base + lane;
      int r = n >> 2;
      int kc = ((n & 3) ^ r ^ (r >> 2)) & 3;
      gld_lds16(A + (size_t)(row0 + r) * lda + k0 + kc * 8, sA + base * 8);
      gld_lds16(B + (size_t)(col0 + r) * K + k0 + kc * 8, sB + base * 8);
    }
    __syncthreads();
    bf16x8 af[4], bfr[4];
#pragma unroll
    for (int i = 0; i < 4; ++i)
      af[i] = *(const bf16x8*)&sA[sw32(wm + i * 16 + l, quad)];
#pragma unroll
    for (int j = 0; j < 4; ++j)
      bfr[j] = *(const bf16x8*)&sB[sw32(wn + j * 16 + l, quad)];
#pragma unroll
    for (int i = 0; i < 4; ++i)
#pragma unroll
      for (int j = 0; j < 4; ++j)
        acc[i][j] = mfma16(af[i], bfr[j], acc[i][j]);
  }
  const bool of32 = (f32flag != nullptr) && (*f32flag != 0);
#pragma unroll
  for (int i = 0; i < 4; ++i) {
    int rr = row0 + wm + i * 16 + quad * 4;
#pragma unroll
    for (int j = 0; j < 4; ++j) {
      int cc = col0 + wn + j * 16 + l;
#pragma unroll
      for (int t = 0; t < 4; ++t) {
        float v = sanit(acc[i][j][t]);
        size_t idx = (size_t)(rr + t) * ldc + cc;
        if (of32) Cf[idx] = v; else Cb[idx] = (bf16_t)v;
      }
    }
  }
}

// ------------- K2: column sumexp L[k]; write Vts = V * (1/L) -----------------
// Grid (bh, kt): same-bh blocks spaced 128 apart -> same XCD -> Q of that bh
// stays L2-hot. Per-lane accj[] defers reduction: 8 atomics/wave.
__global__ __launch_bounds__(256, 4)
void attn_stats(const bf16_t* __restrict__ qkv, bf16_t* __restrict__ Vts) {
  __shared__ bf16_t sK[128 * 64];
  __shared__ bf16_t sV[128 * 64];
  __shared__ float sL[128];
  const int bh = blockIdx.x, kt = blockIdx.y;
  const int b = bh >> 4, h = bh & 15;
  const int tid = threadIdx.x, wave = tid >> 6, lane = tid & 63;
  const int l = lane & 15, quad = lane >> 4;
  const size_t rowK = (size_t)b * 1024 + kt * 128;

  // stage V-tile and K-tile (swizzled)
#pragma unroll
  for (int t = 0; t < 4; ++t) {
    int base = wave * 256 + t * 64;
    int n = base + lane;
    int r = n >> 3;
    int kc = ((n & 7) ^ (r + (r >> 3))) & 7;
    gld_lds16(qkv + (rowK + r) * 3072 + 2048 + h * 64 + kc * 8, sV + base * 8);
    gld_lds16(qkv + (rowK + r) * 3072 + 1024 + h * 64 + kc * 8, sK + base * 8);
  }
  if (tid < 128) sL[tid] = 0.f;
  __syncthreads();

  float accj[8];
#pragma unroll
  for (int j = 0; j < 8; ++j) accj[j] = 0.f;

  for (int qt = 0; qt < 8; ++qt) {
    bf16x8 aq[2][2];
#pragma unroll
    for (int i = 0; i < 2; ++i)
#pragma unroll
      for (int ks = 0; ks < 2; ++ks)
        aq[i][ks] = *(const bf16x8*)&qkv[((size_t)b * 1024 + qt * 128 + wave * 32 +
                                          i * 16 + l) * 3072 + h * 64 +
                                         (ks * 4 + quad) * 8];
#pragma unroll
    for (int j = 0; j < 8; ++j) {
      f32x4 s0 = {0.f, 0.f, 0.f, 0.f}, s1 = {0.f, 0.f, 0.f, 0.f};
#pragma unroll
      for (int ks = 0; ks < 2; ++ks) {
        bf16x8 bk = *(const bf16x8*)&sK[sw64(j * 16 + l, ks * 4 + quad)];
        s0 = mfma16(aq[0][ks], bk, s0);
        s1 = mfma16(aq[1][ks], bk, s1);
      }
#pragma unroll
      for (int t = 0; t < 4; ++t)
        accj[j] += exp2c(s0[t] * C2) + exp2c(s1[t] * C2);
    }
  }
#pragma unroll
  for (int j = 0; j < 8; ++j) {
    float v = accj[j];
    v += __shfl_xor(v, 16);
    v += __shfl_xor(v, 32);
    if (lane < 16) atomicAdd(&sL[j * 16 + l], v);
  }
  __syncthreads();
  if (tid < 128) sL[tid] = 1.0f / fmaxf(sL[tid], 1e-20f);
  __syncthreads();

  // write V transposed & scaled: Vts[bh*64+d][kt*128+k] = V[k][d] * rcpL[k]
#pragma unroll
  for (int t = 0; t < 4; ++t) {
    int u = t * 256 + tid;
    int d = u >> 4, k0 = (u & 15) * 8;
    bf16x8 pk;
#pragma unroll
    for (int i = 0; i < 8; ++i) {
      int k = k0 + i;
      float v = (float)sV[sw64(k, d >> 3) + (d & 7)];
      pk[i] = (bf16_t)(v * sL[k]);
    }
    *(bf16x8*)&Vts[((size_t)bh * 64 + d) * 1024 + kt * 128 + k0] = pk;
  }
}

// ------------- K3: O[q][d] = sum_k exp2(S[q,k]*C2) * Vts[d][k] ---------------
// ZERO barriers: K and Vts fragments read directly from global (each bh's
// 128KB K-tile + 128KB Vts are pinned in its XCD's L2 by the grid swizzle;
// 16 bh/XCD x 256KB = 4MB = one XCD-L2). Only LDS is the wave-private P
// transpose (18KB, rows partitioned by wave). 4 blocks/CU, 16 waves/CU,
// all waves fully asynchronous -- cross-wave MFMA/VALU/exp overlap (m114).
__global__ __launch_bounds__(256, 4)
void attn_out_k(const bf16_t* __restrict__ qkv, const bf16_t* __restrict__ Vts,
                bf16_t* __restrict__ attn) {
  __shared__ bf16_t sP[128 * 72];  // 18 KB, wave-private row ranges
  const int bh = blockIdx.x, qt = blockIdx.y;
  const int b = bh >> 4, h = bh & 15;
  const int tid = threadIdx.x, wave = tid >> 6, lane = tid & 63;
  const int l = lane & 15, quad = lane >> 4;

  const bf16_t* qbase = qkv + (size_t)b * 3145728 + h * 64;  // row stride 3072
  bf16x8 aq[2][2];
#pragma unroll
  for (int i = 0; i < 2; ++i)
#pragma unroll
    for (int ks = 0; ks < 2; ++ks)
      aq[i][ks] = *(const bf16x8*)&qbase[(size_t)(qt * 128 + wave * 32 + i * 16 + l) *
                                             3072 + (ks * 4 + quad) * 8];
  f32x4 o[2][4];
#pragma unroll
  for (int i = 0; i < 2; ++i)
#pragma unroll
    for (int jd = 0; jd < 4; ++jd) o[i][jd] = f32x4{0.f, 0.f, 0.f, 0.f};

  for (int kt = 0; kt < 8; ++kt) {
    const bf16_t* kbase = qbase + 1024 + (size_t)kt * 128 * 3072;
#pragma unroll
    for (int jh = 0; jh < 2; ++jh) {
      // S half: columns [jh*64, jh*64+64); K fragments straight from L2
      f32x4 s[2][4];
#pragma unroll
      for (int j4 = 0; j4 < 4; ++j4) {
        int j = jh * 4 + j4;
        s[0][j4] = f32x4{0.f, 0.f, 0.f, 0.f};
        s[1][j4] = f32x4{0.f, 0.f, 0.f, 0.f};
#pragma unroll
        for (int ks = 0; ks < 2; ++ks) {
          bf16x8 bk = *(const bf16x8*)&kbase[(size_t)(j * 16 + l) * 3072 +
                                             (ks * 4 + quad) * 8];
          s[0][j4] = mfma16(aq[0][ks], bk, s[0][j4]);
          s[1][j4] = mfma16(aq[1][ks], bk, s[1][j4]);
        }
      }
      // P = exp2(S*C2): C-layout -> wave-local sP rows (A-layout readable)
#pragma unroll
      for (int j4 = 0; j4 < 4; ++j4)
#pragma unroll
        for (int i = 0; i < 2; ++i) {
          int row = wave * 32 + i * 16 + quad * 4;
#pragma unroll
          for (int t = 0; t < 4; ++t)
            sP[(row + t) * 72 + j4 * 16 + l] = (bf16_t)exp2c(s[i][j4][t] * C2);
        }
      // O += P_half @ Vts_half (contract 64 k); Vts fragments from L2
#pragma unroll
      for (int ks = 0; ks < 2; ++ks) {
        bf16x8 ap[2];
#pragma unroll
        for (int i = 0; i < 2; ++i)
          ap[i] = *(const bf16x8*)&sP[(wave * 32 + i * 16 + l) * 72 +
                                      (ks * 4 + quad) * 8];
#pragma unroll
        for (int jd = 0; jd < 4; ++jd) {
          bf16x8 bv = *(const bf16x8*)&Vts[((size_t)bh * 64 + jd * 16 + l) * 1024 +
                                           kt * 128 + jh * 64 + (ks * 4 + quad) * 8];
          o[0][jd] = mfma16(ap[0], bv, o[0][jd]);
          o[1][jd] = mfma16(ap[1], bv, o[1][jd]);
        }
      }
    }
  }
  // epilogue: attn rows at stride 3072 (V-columns of qkv, dead after K2)
#pragma unroll
  for (int i = 0; i < 2; ++i) {
    int row = qt * 128 + wave * 32 + i * 16 + quad * 4;
#pragma unroll
    for (int jd = 0; jd < 4; ++jd) {
      int dd = h * 64 + jd * 16 + l;
#pragma unroll
      for (int t = 0; t < 4; ++t)
        attn[((size_t)b * 1024 + row + t) * 3072 + dd] = (bf16_t)sanit(o[i][jd][t]);
    }
  }
}

extern "C" void kernel_launch(void* const* d_in, const int* in_sizes, int n_in,
                              void* d_out, int out_size, void* d_ws, size_t ws_size,
                              hipStream_t stream) {
  (void)in_sizes; (void)n_in; (void)out_size; (void)ws_size;
  char* w = (char*)d_ws;
  bf16_t* qkv = (bf16_t*)w;                 // [0, 50331648)
  bf16_t* xb = (bf16_t*)(w + 50331648);     // [50331648, 67108864) -> Vts after K1
  bf16_t* Vts = xb;
  bf16_t* Wqkvb = (bf16_t*)(w + 67108864);  // [67108864, 73400320)
  bf16_t* Wprojb = (bf16_t*)(w + 73400320); // [73400320, 75497472)
  int* flag = (int*)(w + 75497472);
  bf16_t* attn = qkv + 2048;                // V-columns of qkv, stride 3072

  detect_dtype<<<1, 256, 0, stream>>>((const unsigned short*)d_in[0], flag);
  convert_in<<<6144, 256, 0, stream>>>(d_in[0], d_in[1], d_in[2],
                                       xb, Wqkvb, Wprojb, flag);

  // K1: qkv = x @ Wqkv^T  (8192 x 3072, K=1024)
  gemm_bt<<<dim3(24, 64), 256, 0, stream>>>(xb, 1024, Wqkvb, qkv, nullptr, 3072,
                                            1024, nullptr);
  // K2: column-softmax denominators folded into Vts
  attn_stats<<<dim3(128, 8), 256, 0, stream>>>(qkv, Vts);
  // K3: attention output -> qkv V-columns
  attn_out_k<<<dim3(128, 8), 256, 0, stream>>>(qkv, Vts, attn);
  // K4: out = attn @ Wproj^T  (8192 x 1024, K=1024), dtype per flag
  gemm_bt<<<dim3(8, 64), 256, 0, stream>>>(attn, 3072, Wprojb, (bf16_t*)d_out,
                                           (float*)d_out, 1024, 1024, flag);
}

// Round 8
// 316.475 us; speedup vs baseline: 1.1093x; 1.1093x over previous
//
#include <hip/hip_runtime.h>

// B=8, T=1024, D=1024, H=16, DH=64.
// Column softmax (axis=-2): attn[q,k] = exp(S[q,k])/sum_q' exp(S[q',k]).
// rcpL folded into V (Vts = V * rcpL), so K3 is O = exp2(S*C2) @ Vts.
// K3 computes S TRANSPOSED (A=K, B=Q) so the P fragment exits MFMA with
// q=lane&15 -- already matching the PV B-operand layout; only k needs a
// wave-local quad redistribution (2 ds_write_b64 + 1 ds_read_b128).

typedef __bf16 bf16_t;
typedef __bf16 bf16x8 __attribute__((ext_vector_type(8)));
typedef __bf16 bf16x4 __attribute__((ext_vector_type(4)));
typedef float f32x4 __attribute__((ext_vector_type(4)));
typedef unsigned short u16x8 __attribute__((ext_vector_type(8)));

#define DEV __device__ __forceinline__
#define C2 0.18033688f  // DH^-0.5 * log2(e)

DEV void gld_lds16(const bf16_t* g, bf16_t* l) {
  __builtin_amdgcn_global_load_lds(
      (const __attribute__((address_space(1))) unsigned int*)g,
      (__attribute__((address_space(3))) unsigned int*)l, 16, 0, 0);
}

// exp2 via v_exp_f32; upper clamp only (underflow->0 fine); finite always.
DEV float exp2c(float x) { return __builtin_amdgcn_exp2f(fminf(x, 30.f)); }
DEV float sanit(float v) { return (v == v) ? fminf(fmaxf(v, -1e4f), 1e4f) : 0.f; }

// Swizzled chunk (8 bf16 = 16B) offsets in elements. Swizzle baked into the
// staging GLOBAL address so the LDS side stays linear (global_load_lds req).
DEV int sw64(int r, int kc) { return r * 64 + (((kc ^ (r + (r >> 3))) & 7) << 3); }
DEV int sw32(int r, int kc) { return r * 32 + (((kc ^ r ^ (r >> 2)) & 3) << 3); }

DEV f32x4 mfma16(bf16x8 a, bf16x8 b, f32x4 c) {
  return __builtin_amdgcn_mfma_f32_16x16x32_bf16(a, b, c, 0, 0, 0);
}

// ---- dtype probe: bf16 data has exp<=~134; fp32 misread shows exp>=160 -----
__global__ void detect_dtype(const unsigned short* x, int* flag) {
  __shared__ int smax;
  if (threadIdx.x == 0) smax = 0;
  __syncthreads();
  int m = 0;
  for (int i = threadIdx.x; i < 16384; i += 256) {
    int e = (x[i] >> 7) & 0xFF;
    m = m > e ? m : e;
  }
  atomicMax(&smax, m);
  __syncthreads();
  if (threadIdx.x == 0) *flag = (smax >= 160) ? 1 : 0;
}

// ---- canonicalize all 3 inputs to bf16 in one kernel ------------------------
__global__ void convert_in(const void* __restrict__ x, const void* __restrict__ wq,
                           const void* __restrict__ wp, bf16_t* __restrict__ xb,
                           bf16_t* __restrict__ wqb, bf16_t* __restrict__ wpb,
                           const int* __restrict__ flag) {
  int i = blockIdx.x * 256 + threadIdx.x;  // vec8 index, total 1572864
  const void* src;
  bf16_t* dst;
  int off;
  if (i < 1048576) { src = x; dst = xb; off = i; }
  else if (i < 1441792) { src = wq; dst = wqb; off = i - 1048576; }
  else { src = wp; dst = wpb; off = i - 1441792; }
  if (*flag) {
    const float4* s = (const float4*)src;
    float4 a = s[off * 2], b = s[off * 2 + 1];
    bf16x8 o;
    o[0] = (bf16_t)a.x; o[1] = (bf16_t)a.y; o[2] = (bf16_t)a.z; o[3] = (bf16_t)a.w;
    o[4] = (bf16_t)b.x; o[5] = (bf16_t)b.y; o[6] = (bf16_t)b.z; o[7] = (bf16_t)b.w;
    *(bf16x8*)(dst + (size_t)off * 8) = o;
  } else {
    ((u16x8*)dst)[off] = ((const u16x8*)src)[off];
  }
}

// --------- C[m][n] = sum_k A[m][k]*B[n][k], 128x128 tile, BK=32 -------------
__global__ __launch_bounds__(256, 2)
void gemm_bt(const bf16_t* __restrict__ A, int lda, const bf16_t* __restrict__ B,
             bf16_t* __restrict__ Cb, float* __restrict__ Cf, int ldc,
             int K, const int* __restrict__ f32flag) {
  __shared__ bf16_t sA[128 * 32];
  __shared__ bf16_t sB[128 * 32];
  const int tid = threadIdx.x;
  const int wave = tid >> 6, lane = tid & 63;
  const int l = lane & 15, quad = lane >> 4;
  const int row0 = blockIdx.y * 128, col0 = blockIdx.x * 128;
  const int wm = (wave >> 1) * 64, wn = (wave & 1) * 64;
  f32x4 acc[4][4];
#pragma unroll
  for (int i = 0; i < 4; ++i)
#pragma unroll
    for (int j = 0; j < 4; ++j) acc[i][j] = f32x4{0.f, 0.f, 0.f, 0.f};

  for (int k0 = 0; k0 < K; k0 += 32) {
    __syncthreads();
#pragma unroll
    for (int t = 0; t < 2; ++t) {
      int base = t * 256 + wave * 64;
      int n = base + lane;
      int r = n >> 2;
      int kc = ((n & 3) ^ r ^ (r >> 2)) & 3;
      gld_lds16(A + (size_t)(row0 + r) * lda + k0 + kc * 8, sA + base * 8);
      gld_lds16(B + (size_t)(col0 + r) * K + k0 + kc * 8, sB + base * 8);
    }
    __syncthreads();
    bf16x8 af[4], bfr[4];
#pragma unroll
    for (int i = 0; i < 4; ++i)
      af[i] = *(const bf16x8*)&sA[sw32(wm + i * 16 + l, quad)];
#pragma unroll
    for (int j = 0; j < 4; ++j)
      bfr[j] = *(const bf16x8*)&sB[sw32(wn + j * 16 + l, quad)];
#pragma unroll
    for (int i = 0; i < 4; ++i)
#pragma unroll
      for (int j = 0; j < 4; ++j)
        acc[i][j] = mfma16(af[i], bfr[j], acc[i][j]);
  }
  const bool of32 = (f32flag != nullptr) && (*f32flag != 0);
#pragma unroll
  for (int i = 0; i < 4; ++i) {
    int rr = row0 + wm + i * 16 + quad * 4;
#pragma unroll
    for (int j = 0; j < 4; ++j) {
      int cc = col0 + wn + j * 16 + l;
#pragma unroll
      for (int t = 0; t < 4; ++t) {
        float v = sanit(acc[i][j][t]);
        size_t idx = (size_t)(rr + t) * ldc + cc;
        if (of32) Cf[idx] = v; else Cb[idx] = (bf16_t)v;
      }
    }
  }
}

// ------------- K2: column sumexp L[k]; write Vts = V * (1/L) -----------------
// Grid (bh, kt): same-bh blocks spaced 128 apart -> same XCD -> Q of that bh
// stays L2-hot. Per-lane accj[] defers reduction: 8 atomics/wave.
__global__ __launch_bounds__(256, 4)
void attn_stats(const bf16_t* __restrict__ qkv, bf16_t* __restrict__ Vts) {
  __shared__ bf16_t sK[128 * 64];
  __shared__ bf16_t sV[128 * 64];
  __shared__ float sL[128];
  const int bh = blockIdx.x, kt = blockIdx.y;
  const int b = bh >> 4, h = bh & 15;
  const int tid = threadIdx.x, wave = tid >> 6, lane = tid & 63;
  const int l = lane & 15, quad = lane >> 4;
  const size_t rowK = (size_t)b * 1024 + kt * 128;

  // stage V-tile and K-tile (swizzled)
#pragma unroll
  for (int t = 0; t < 4; ++t) {
    int base = wave * 256 + t * 64;
    int n = base + lane;
    int r = n >> 3;
    int kc = ((n & 7) ^ (r + (r >> 3))) & 7;
    gld_lds16(qkv + (rowK + r) * 3072 + 2048 + h * 64 + kc * 8, sV + base * 8);
    gld_lds16(qkv + (rowK + r) * 3072 + 1024 + h * 64 + kc * 8, sK + base * 8);
  }
  if (tid < 128) sL[tid] = 0.f;
  __syncthreads();

  float accj[8];
#pragma unroll
  for (int j = 0; j < 8; ++j) accj[j] = 0.f;

  for (int qt = 0; qt < 8; ++qt) {
    bf16x8 aq[2][2];
#pragma unroll
    for (int i = 0; i < 2; ++i)
#pragma unroll
      for (int ks = 0; ks < 2; ++ks)
        aq[i][ks] = *(const bf16x8*)&qkv[((size_t)b * 1024 + qt * 128 + wave * 32 +
                                          i * 16 + l) * 3072 + h * 64 +
                                         (ks * 4 + quad) * 8];
#pragma unroll
    for (int j = 0; j < 8; ++j) {
      f32x4 s0 = {0.f, 0.f, 0.f, 0.f}, s1 = {0.f, 0.f, 0.f, 0.f};
#pragma unroll
      for (int ks = 0; ks < 2; ++ks) {
        bf16x8 bk = *(const bf16x8*)&sK[sw64(j * 16 + l, ks * 4 + quad)];
        s0 = mfma16(aq[0][ks], bk, s0);
        s1 = mfma16(aq[1][ks], bk, s1);
      }
#pragma unroll
      for (int t = 0; t < 4; ++t)
        accj[j] += exp2c(s0[t] * C2) + exp2c(s1[t] * C2);
    }
  }
#pragma unroll
  for (int j = 0; j < 8; ++j) {
    float v = accj[j];
    v += __shfl_xor(v, 16);
    v += __shfl_xor(v, 32);
    if (lane < 16) atomicAdd(&sL[j * 16 + l], v);
  }
  __syncthreads();
  if (tid < 128) sL[tid] = 1.0f / fmaxf(sL[tid], 1e-20f);
  __syncthreads();

  // write V transposed & scaled: Vts[bh*64+d][kt*128+k] = V[k][d] * rcpL[k]
#pragma unroll
  for (int t = 0; t < 4; ++t) {
    int u = t * 256 + tid;
    int d = u >> 4, k0 = (u & 15) * 8;
    bf16x8 pk;
#pragma unroll
    for (int i = 0; i < 8; ++i) {
      int k = k0 + i;
      float v = (float)sV[sw64(k, d >> 3) + (d & 7)];
      pk[i] = (bf16_t)(v * sL[k]);
    }
    *(bf16x8*)&Vts[((size_t)bh * 64 + d) * 1024 + kt * 128 + k0] = pk;
  }
}

// ------------- K3: O[q][d] = sum_k exp2(S[q,k]*C2) * Vts[d][k] ---------------
// S computed TRANSPOSED: st = K-frag x Q-frag -> S^T[k=quad*4+t][q=l].
// P^T fragment: q=l already matches PV B-operand (B[n=q=l][k=quad*8+j]);
// k redistributed across quads via per-wave 16x40 LDS buffer
// (2 ds_write_b64 + 1 ds_read_b128 per 32k x 16q unit, bank-clean, no barrier).
// PV: A=Vts (m=d), D[m=d][n=q] -> epilogue packs 4 consecutive d per store.
// K-tile: global_load_lds double-buffer, 1 barrier/kt. LDS 37.9KB, 4 blk/CU.
__global__ __launch_bounds__(256, 4)
void attn_out_k(const bf16_t* __restrict__ qkv, const bf16_t* __restrict__ Vts,
                bf16_t* __restrict__ attn) {
  __shared__ bf16_t sK[2][128 * 64];  // 32 KB dbuf
  __shared__ bf16_t sT[4][16 * 40];   // 5 KB per-wave transpose buffers
  const int bh = blockIdx.x, qt = blockIdx.y;
  const int b = bh >> 4, h = bh & 15;
  const int tid = threadIdx.x, wave = tid >> 6, lane = tid & 63;
  const int l = lane & 15, quad = lane >> 4;
  const bf16_t* qbase = qkv + (size_t)b * 3145728 + h * 64;  // row stride 3072

  // Q B-fragments (loop-invariant): B[n=q][dk = ks*32 + quad*8 + j]
  bf16x8 bq[2][2];
#pragma unroll
  for (int i = 0; i < 2; ++i)
#pragma unroll
    for (int ks = 0; ks < 2; ++ks)
      bq[i][ks] = *(const bf16x8*)&qbase[(size_t)(qt * 128 + wave * 32 + i * 16 + l) *
                                             3072 + ks * 32 + quad * 8];
  f32x4 o[2][4];  // o[i=qtile][jd=dtile] : D[m=d][n=q]
#pragma unroll
  for (int i = 0; i < 2; ++i)
#pragma unroll
    for (int jd = 0; jd < 4; ++jd) o[i][jd] = f32x4{0.f, 0.f, 0.f, 0.f};

  // stage K[0] -> buf 0
#pragma unroll
  for (int t = 0; t < 4; ++t) {
    int base = wave * 256 + t * 64;
    int n = base + lane;
    int r = n >> 3;
    int kc = ((n & 7) ^ (r + (r >> 3))) & 7;
    gld_lds16(qkv + ((size_t)b * 1024 + r) * 3072 + 1024 + h * 64 + kc * 8,
              sK[0] + base * 8);
  }
  bf16_t* sTw = sT[wave];

  for (int kt = 0; kt < 8; ++kt) {
    const int buf = kt & 1;
    __syncthreads();  // drains stage(kt); orders buf^1 refill vs prev reads
    if (kt < 7) {
#pragma unroll
      for (int t = 0; t < 4; ++t) {
        int base = wave * 256 + t * 64;
        int n = base + lane;
        int r = n >> 3;
        int kc = ((n & 7) ^ (r + (r >> 3))) & 7;
        gld_lds16(qkv + ((size_t)b * 1024 + (kt + 1) * 128 + r) * 3072 + 1024 +
                      h * 64 + kc * 8,
                  sK[buf ^ 1] + base * 8);
      }
    }
    const bf16_t* sKb = sK[buf];

#pragma unroll
    for (int ch = 0; ch < 4; ++ch) {  // 32-k chunks
      // Vts A-frags: A[m=d=jd*16+l][k=quad*8+j], shared by both q-tiles
      bf16x8 av[4];
#pragma unroll
      for (int jd = 0; jd < 4; ++jd)
        av[jd] = *(const bf16x8*)&Vts[((size_t)bh * 64 + jd * 16 + l) * 1024 +
                                      kt * 128 + ch * 32 + quad * 8];
#pragma unroll
      for (int i = 0; i < 2; ++i) {  // q-tiles
        // S^T tiles (kk=0,1): A=K-frag A[m=k=ch*32+kk*16+l][dk]
        f32x4 st[2];
#pragma unroll
        for (int kk = 0; kk < 2; ++kk) {
          st[kk] = f32x4{0.f, 0.f, 0.f, 0.f};
#pragma unroll
          for (int ks = 0; ks < 2; ++ks) {
            bf16x8 ak = *(const bf16x8*)&sKb[sw64(ch * 32 + kk * 16 + l,
                                                  ks * 4 + quad)];
            st[kk] = mfma16(ak, bq[i][ks], st[kk]);
          }
        }
        // P^T = exp2(S^T*C2): write k=kk*16+quad*4+{0..3} packed at row q=l
#pragma unroll
        for (int kk = 0; kk < 2; ++kk) {
          bf16x4 pk;
#pragma unroll
          for (int t = 0; t < 4; ++t) pk[t] = (bf16_t)exp2c(st[kk][t] * C2);
          *(bf16x4*)&sTw[l * 40 + kk * 16 + quad * 4] = pk;
        }
        // B-frag: B[n=q=l][k=quad*8+j]  (compiler orders via lgkmcnt)
        bf16x8 bp = *(const bf16x8*)&sTw[l * 40 + quad * 8];
#pragma unroll
        for (int jd = 0; jd < 4; ++jd)
          o[i][jd] = mfma16(av[jd], bp, o[i][jd]);
      }
    }
  }
  // epilogue: q = qt*128+wave*32+i*16+l, d = jd*16+quad*4+{0..3} -> 8B stores
#pragma unroll
  for (int i = 0; i < 2; ++i) {
    size_t row = (size_t)b * 1024 + qt * 128 + wave * 32 + i * 16 + l;
#pragma unroll
    for (int jd = 0; jd < 4; ++jd) {
      bf16x4 pk;
#pragma unroll
      for (int t = 0; t < 4; ++t) pk[t] = (bf16_t)sanit(o[i][jd][t]);
      *(bf16x4*)&attn[row * 3072 + h * 64 + jd * 16 + quad * 4] = pk;
    }
  }
}

extern "C" void kernel_launch(void* const* d_in, const int* in_sizes, int n_in,
                              void* d_out, int out_size, void* d_ws, size_t ws_size,
                              hipStream_t stream) {
  (void)in_sizes; (void)n_in; (void)out_size; (void)ws_size;
  char* w = (char*)d_ws;
  bf16_t* qkv = (bf16_t*)w;                 // [0, 50331648)
  bf16_t* xb = (bf16_t*)(w + 50331648);     // [50331648, 67108864) -> Vts after K1
  bf16_t* Vts = xb;
  bf16_t* Wqkvb = (bf16_t*)(w + 67108864);  // [67108864, 73400320)
  bf16_t* Wprojb = (bf16_t*)(w + 73400320); // [73400320, 75497472)
  int* flag = (int*)(w + 75497472);
  bf16_t* attn = qkv + 2048;                // V-columns of qkv, stride 3072

  detect_dtype<<<1, 256, 0, stream>>>((const unsigned short*)d_in[0], flag);
  convert_in<<<6144, 256, 0, stream>>>(d_in[0], d_in[1], d_in[2],
                                       xb, Wqkvb, Wprojb, flag);

  // K1: qkv = x @ Wqkv^T  (8192 x 3072, K=1024)
  gemm_bt<<<dim3(24, 64), 256, 0, stream>>>(xb, 1024, Wqkvb, qkv, nullptr, 3072,
                                            1024, nullptr);
  // K2: column-softmax denominators folded into Vts
  attn_stats<<<dim3(128, 8), 256, 0, stream>>>(qkv, Vts);
  // K3: attention output -> qkv V-columns
  attn_out_k<<<dim3(128, 8), 256, 0, stream>>>(qkv, Vts, attn);
  // K4: out = attn @ Wproj^T  (8192 x 1024, K=1024), dtype per flag
  gemm_bt<<<dim3(8, 64), 256, 0, stream>>>(attn, 3072, Wprojb, (bf16_t*)d_out,
                                           (float*)d_out, 1024, 1024, flag);
}